// Round 18
// baseline (256.034 us; speedup 1.0000x reference)
//
#include <hip/hip_runtime.h>
#include <hip/hip_bf16.h>

#define HID 512
#define BATCH 2048

typedef __bf16 bf16x8 __attribute__((ext_vector_type(8)));
typedef float f32x4 __attribute__((ext_vector_type(4)));
typedef float f32x16 __attribute__((ext_vector_type(16)));
typedef __hip_bfloat16 bf16;

__device__ inline unsigned short f2bf(float x) {
    bf16 h = __float2bfloat16(x);
    return __builtin_bit_cast(unsigned short, h);
}
__device__ inline float bf2f(unsigned short u) {
    return __bfloat162float(__builtin_bit_cast(bf16, u));
}

__device__ inline void gload16(const void* g, void* l) {
    __builtin_amdgcn_global_load_lds((const __attribute__((address_space(1))) void*)g,
                                     (__attribute__((address_space(3))) void*)l, 16, 0, 0);
}

// ---------------- prep: weight hi/lo split (s2, m1, m3) + layer-0 rank-2 GEMV ----------------
struct CvtArgs { const float* src[7]; };   // s2_W, m1 q/k/v, m3 q/k/v

__global__ void k_prep(CvtArgs a, unsigned short* __restrict__ hi, unsigned short* __restrict__ lo,
                       const float* __restrict__ s0W, const float* __restrict__ s0b,
                       const float* __restrict__ ipw, const float* __restrict__ ipb,
                       float* __restrict__ uV, float* __restrict__ uT, float* __restrict__ uC) {
    const int bid = blockIdx.x;
    if (bid < 2560) {   // cvt: 2,621,440 elems / 4 / 256
        int idx4 = (bid * 256 + threadIdx.x) << 2;
        int seg, off; size_t dst;
        if (idx4 < 1048576) { seg = 0; off = idx4; dst = 1048576 + idx4; }          // s2_W
        else { int r = idx4 - 1048576; seg = 1 + (r >> 18); off = r & 262143; dst = 2097152 + r; }
        f32x4 w = *(const f32x4*)(a.src[seg] + off);
        ushort4 h, l;
        h.x = f2bf(w[0]); h.y = f2bf(w[1]); h.z = f2bf(w[2]); h.w = f2bf(w[3]);
        l.x = f2bf(w[0] - bf2f(h.x)); l.y = f2bf(w[1] - bf2f(h.y));
        l.z = f2bf(w[2] - bf2f(h.z)); l.w = f2bf(w[3] - bf2f(h.w));
        *(ushort4*)(hi + dst) = h;
        *(ushort4*)(lo + dst) = l;
    } else {            // GEMV: 1536 gate rows (skip f-rows 512-1023), 4 waves/block
        const int w = threadIdx.x >> 6, lane = threadIdx.x & 63;
        const int r = (bid - 2560) * 4 + w;            // compact row 0..1535
        const int wr = r < 512 ? r : r + 512;          // W row (i / g / o segments)
        const float* Wp = s0W + (size_t)wr * HID + lane * 8;
        f32x4 wa = *(const f32x4*)Wp, wb = *(const f32x4*)(Wp + 4);
        const float* pw = ipw + lane * 16;             // [HID][2] interleaved
        f32x4 e0 = *(const f32x4*)pw,       e1 = *(const f32x4*)(pw + 4);
        f32x4 e2 = *(const f32x4*)(pw + 8), e3 = *(const f32x4*)(pw + 12);
        f32x4 ba = *(const f32x4*)(ipb + lane * 8), bb = *(const f32x4*)(ipb + lane * 8 + 4);
        float s0 = wa[0]*e0[0] + wa[1]*e0[2] + wa[2]*e1[0] + wa[3]*e1[2]
                 + wb[0]*e2[0] + wb[1]*e2[2] + wb[2]*e3[0] + wb[3]*e3[2];
        float s1 = wa[0]*e0[1] + wa[1]*e0[3] + wa[2]*e1[1] + wa[3]*e1[3]
                 + wb[0]*e2[1] + wb[1]*e2[3] + wb[2]*e3[1] + wb[3]*e3[3];
        float s2 = wa[0]*ba[0] + wa[1]*ba[1] + wa[2]*ba[2] + wa[3]*ba[3]
                 + wb[0]*bb[0] + wb[1]*bb[1] + wb[2]*bb[2] + wb[3]*bb[3];
#pragma unroll
        for (int off = 32; off; off >>= 1) {
            s0 += __shfl_xor(s0, off); s1 += __shfl_xor(s1, off); s2 += __shfl_xor(s2, off);
        }
        if (lane == 0) { uV[r] = s0; uT[r] = s1; uC[r] = s2 + s0b[wr]; }
    }
}

// ---------------- layer-1 GEMM with fused layer-0 sLSTM A-generation ----------------
// A[row][k] = act(V[row]*uV' + t[row]*uT' + uC') computed in-kernel (rank-2 trick),
// split hi/lo, ds_written into the pipeline. W staged via gload_lds (waves 4-7).
// Blocks with n0==0 also side-write hB (hi/lo) to global for k_mlstm's input gate.
__global__ __launch_bounds__(512) void k_gemm1(
    const float* __restrict__ Vin, const float* __restrict__ Tin,
    const float* __restrict__ uVg, const float* __restrict__ uTg, const float* __restrict__ uCg,
    const bf16* __restrict__ Wh0, const bf16* __restrict__ Wh1, const bf16* __restrict__ Wh2,
    const bf16* __restrict__ Wl0, const bf16* __restrict__ Wl1, const bf16* __restrict__ Wl2,
    unsigned short* __restrict__ hBhi, unsigned short* __restrict__ hBlo,
    float* __restrict__ C)
{
    __shared__ __align__(16) bf16 lds[5][8192];   // 80 KB staging
    __shared__ __align__(16) float ubuf[4608];    // 18 KB rank-2 tables
    const int tid = threadIdx.x, w = tid >> 6, lane = tid & 63;

    const int bid = blockIdx.x;                   // 192 blocks: 8 XCD x 24 slots
    const int xcd = bid & 7, slot = bid >> 3;
    const int m0 = (xcd * 2 + slot / 12) * 128;
    const int n0 = (slot % 12) * 128;
    const int nseg = n0 >> 9, nloc = n0 & 511;
    const bf16* Wh = nseg == 0 ? Wh0 : (nseg == 1 ? Wh1 : Wh2);
    const bf16* Wl = nseg == 0 ? Wl0 : (nseg == 1 ? Wl1 : Wl2);
    const bool whb = (slot % 12) == 0;            // 16 blocks cover all m-slabs exactly once

    for (int i = tid; i < 1536; i += 512) {
        ubuf[i] = uVg[i];
        ubuf[1536 + i] = uTg[i];
        ubuf[3072 + i] = uCg[i];
    }

    // W staging: wave w>=4 stages chunks 2w, 2w+1 (8..15 = Wh rb0-3, Wl rb0-3)
    const int cw = (w >= 4) ? 2 * w : 8;
    auto wsrc = [&](int c) -> const bf16* {
        const bf16* base = ((c >> 2) == 2) ? Wh : Wl;
        return base + (size_t)(nloc + ((c & 3) << 5) + (lane & 31)) * HID + ((lane >> 5) << 3);
    };
    const bf16* sp0 = wsrc(cw);
    const bf16* sp1 = wsrc(cw + 1);
    bf16* const wdst = &lds[0][0] + (cw << 9) + (lane << 3);

    // A-gen mapping: all 8 waves, 4 elems/thread/step
    const int rb = w & 3;
    const int grow = m0 + (rb << 5) + (lane & 31);
    const int kpart = ((w >> 2) << 3) + ((lane >> 5) << 2);
    const float Vv = Vin[grow], Tv = Tin[grow];
    const int aoff = ((lane & 31) << 4) + ((w >> 2) << 9) + ((lane >> 5) << 3);  // bytes in chunk

    auto AGEN = [&](int t) {
        const int kk = (t << 4) + kpart;
        f32x4 vi = *(const f32x4*)&ubuf[kk];
        f32x4 ti = *(const f32x4*)&ubuf[1536 + kk];
        f32x4 ci = *(const f32x4*)&ubuf[3072 + kk];
        f32x4 vg = *(const f32x4*)&ubuf[512 + kk];
        f32x4 tg = *(const f32x4*)&ubuf[2048 + kk];
        f32x4 cg = *(const f32x4*)&ubuf[3584 + kk];
        f32x4 vo = *(const f32x4*)&ubuf[1024 + kk];
        f32x4 to = *(const f32x4*)&ubuf[2560 + kk];
        f32x4 co = *(const f32x4*)&ubuf[4096 + kk];
        ushort4 h4, l4;
#pragma unroll
        for (int j = 0; j < 4; ++j) {
            float gi = Vv * vi[j] + Tv * ti[j] + ci[j];
            float gg = Vv * vg[j] + Tv * tg[j] + cg[j];
            float go = Vv * vo[j] + Tv * to[j] + co[j];
            float x = tanhf(expf(gi) * tanhf(gg)) / (1.f + expf(-go));
            unsigned short hh = f2bf(x);
            unsigned short ll = f2bf(x - bf2f(hh));
            if (j == 0) { h4.x = hh; l4.x = ll; }
            else if (j == 1) { h4.y = hh; l4.y = ll; }
            else if (j == 2) { h4.z = hh; l4.z = ll; }
            else { h4.w = hh; l4.w = ll; }
        }
        char* lb = (char*)&lds[t % 5][0];
        *(ushort4*)(lb + (rb << 10) + aoff) = h4;             // Ah chunk rb
        *(ushort4*)(lb + ((4 + rb) << 10) + aoff) = l4;       // Al chunk 4+rb
        if (whb) {
            *(ushort4*)(hBhi + (size_t)grow * HID + kk) = h4;
            *(ushort4*)(hBlo + (size_t)grow * HID + kk) = l4;
        }
    };
    auto WSTAGE = [&](int t) {
        if (w >= 4) {
            bf16* db = wdst + (t % 5) * 8192;
            gload16(sp0 + (t << 4), db);
            gload16(sp1 + (t << 4), db + 512);
        }
    };

    __syncthreads();   // ubuf ready before A-gen reads it
    WSTAGE(0); AGEN(0); WSTAGE(1); AGEN(1); WSTAGE(2); AGEN(2); WSTAGE(3); AGEN(3);

    const int wm = w >> 1, wn = w & 1;
    const int la = lane << 3;
    const int cA  = wm << 9;
    const int cAl = (4 + wm) << 9;
    const int cW0 = (8 + 2 * wn) << 9;
    const int cW1 = (9 + 2 * wn) << 9;
    const int cL0 = (12 + 2 * wn) << 9;
    const int cL1 = (13 + 2 * wn) << 9;
    f32x16 acc0 = {}, acc1 = {};

#pragma unroll
    for (int t = 0; t < 32; ++t) {
        if (t < 28) {
            if (whb) asm volatile("s_waitcnt vmcnt(14) lgkmcnt(0)" ::: "memory");
            else     asm volatile("s_waitcnt vmcnt(6) lgkmcnt(0)" ::: "memory");
        } else {
            asm volatile("s_waitcnt vmcnt(0) lgkmcnt(0)" ::: "memory");
        }
        asm volatile("s_barrier" ::: "memory");
        if (t < 28) { WSTAGE(t + 4); AGEN(t + 4); }   // writes buf (t+4)%5=(t-1)%5: drained
        const bf16* lb = &lds[t % 5][0];
        bf16x8 ah  = *(const bf16x8*)(lb + cA  + la);
        bf16x8 al  = *(const bf16x8*)(lb + cAl + la);
        bf16x8 wh0 = *(const bf16x8*)(lb + cW0 + la);
        bf16x8 wh1 = *(const bf16x8*)(lb + cW1 + la);
        bf16x8 wl0 = *(const bf16x8*)(lb + cL0 + la);
        bf16x8 wl1 = *(const bf16x8*)(lb + cL1 + la);
        acc0 = __builtin_amdgcn_mfma_f32_32x32x16_bf16(ah, wh0, acc0, 0, 0, 0);
        acc1 = __builtin_amdgcn_mfma_f32_32x32x16_bf16(ah, wh1, acc1, 0, 0, 0);
        acc0 = __builtin_amdgcn_mfma_f32_32x32x16_bf16(al, wh0, acc0, 0, 0, 0);
        acc1 = __builtin_amdgcn_mfma_f32_32x32x16_bf16(al, wh1, acc1, 0, 0, 0);
        acc0 = __builtin_amdgcn_mfma_f32_32x32x16_bf16(ah, wl0, acc0, 0, 0, 0);
        acc1 = __builtin_amdgcn_mfma_f32_32x32x16_bf16(ah, wl1, acc1, 0, 0, 0);
    }

    const int rb4 = (lane >> 5) << 2;
#pragma unroll
    for (int f = 0; f < 2; ++f) {
        const f32x16& ac = f ? acc1 : acc0;
        const int col = n0 + ((2 * wn + f) << 5) + (lane & 31);
#pragma unroll
        for (int rr = 0; rr < 16; ++rr) {
            int row = m0 + (wm << 5) + (rr & 3) + ((rr >> 2) << 3) + rb4;
            C[(size_t)row * 1536 + col] = ac[rr];
        }
    }
}

// ---------------- native-K split-bf16 GEMM (L2/L3): 8 waves, 5-buffer pipeline ----------------
__global__ __launch_bounds__(512) void k_gemm(
    const bf16* __restrict__ Ahi, const bf16* __restrict__ Alo,
    const bf16* __restrict__ Wh0, const bf16* __restrict__ Wh1, const bf16* __restrict__ Wh2,
    const bf16* __restrict__ Wl0, const bf16* __restrict__ Wl1, const bf16* __restrict__ Wl2,
    float* __restrict__ C)
{
    __shared__ __align__(16) bf16 lds[5][8192];   // 80 KB
    const int tid = threadIdx.x, w = tid >> 6, lane = tid & 63;

    const int bid = blockIdx.x;                   // 192 blocks: 8 XCD x 24 slots
    const int xcd = bid & 7, slot = bid >> 3;
    const int m0 = (xcd * 2 + slot / 12) * 128;
    const int n0 = (slot % 12) * 128;
    const int nseg = n0 >> 9, nloc = n0 & 511;
    const bf16* Wh = nseg == 0 ? Wh0 : (nseg == 1 ? Wh1 : Wh2);
    const bf16* Wl = nseg == 0 ? Wl0 : (nseg == 1 ? Wl1 : Wl2);

    auto src_of = [&](int c) -> const bf16* {
        const int m = c >> 2, rb = c & 3;
        const bf16* base = (m == 0) ? Ahi : (m == 1) ? Alo : (m == 2) ? Wh : Wl;
        const int rowbase = (m < 2) ? m0 : nloc;
        return base + (size_t)(rowbase + (rb << 5) + (lane & 31)) * HID + ((lane >> 5) << 3);
    };
    const int c0 = 2 * w;
    const bf16* sp0 = src_of(c0);
    const bf16* sp1 = src_of(c0 + 1);
    bf16* const d0 = &lds[0][0] + (c0 << 9) + (lane << 3);

    auto STAGE = [&](int t) {
        bf16* db = d0 + (t % 5) * 8192;
        gload16(sp0 + (t << 4), db);
        gload16(sp1 + (t << 4), db + 512);
    };

    const int wm = w >> 1, wn = w & 1;
    const int la = lane << 3;
    const int cA  = wm << 9;
    const int cAl = (4 + wm) << 9;
    const int cW0 = (8 + 2 * wn) << 9;
    const int cW1 = (9 + 2 * wn) << 9;
    const int cL0 = (12 + 2 * wn) << 9;
    const int cL1 = (13 + 2 * wn) << 9;
    f32x16 acc0 = {}, acc1 = {};

    STAGE(0); STAGE(1); STAGE(2); STAGE(3);
#pragma unroll
    for (int t = 0; t < 32; ++t) {
        if (t < 29)
            asm volatile("s_waitcnt vmcnt(6) lgkmcnt(0)\n\ts_barrier" ::: "memory");
        else if (t == 29)
            asm volatile("s_waitcnt vmcnt(4) lgkmcnt(0)\n\ts_barrier" ::: "memory");
        else if (t == 30)
            asm volatile("s_waitcnt vmcnt(2) lgkmcnt(0)\n\ts_barrier" ::: "memory");
        else
            asm volatile("s_waitcnt vmcnt(0) lgkmcnt(0)\n\ts_barrier" ::: "memory");
        if (t < 28) STAGE(t + 4);
        const bf16* lb = &lds[t % 5][0];
        bf16x8 ah  = *(const bf16x8*)(lb + cA  + la);
        bf16x8 al  = *(const bf16x8*)(lb + cAl + la);
        bf16x8 wh0 = *(const bf16x8*)(lb + cW0 + la);
        bf16x8 wh1 = *(const bf16x8*)(lb + cW1 + la);
        bf16x8 wl0 = *(const bf16x8*)(lb + cL0 + la);
        bf16x8 wl1 = *(const bf16x8*)(lb + cL1 + la);
        acc0 = __builtin_amdgcn_mfma_f32_32x32x16_bf16(ah, wh0, acc0, 0, 0, 0);
        acc1 = __builtin_amdgcn_mfma_f32_32x32x16_bf16(ah, wh1, acc1, 0, 0, 0);
        acc0 = __builtin_amdgcn_mfma_f32_32x32x16_bf16(al, wh0, acc0, 0, 0, 0);
        acc1 = __builtin_amdgcn_mfma_f32_32x32x16_bf16(al, wh1, acc1, 0, 0, 0);
        acc0 = __builtin_amdgcn_mfma_f32_32x32x16_bf16(ah, wl0, acc0, 0, 0, 0);
        acc1 = __builtin_amdgcn_mfma_f32_32x32x16_bf16(ah, wl1, acc1, 0, 0, 0);
    }

    const int rb4 = (lane >> 5) << 2;
#pragma unroll
    for (int f = 0; f < 2; ++f) {
        const f32x16& ac = f ? acc1 : acc0;
        const int col = n0 + ((2 * wn + f) << 5) + (lane & 31);
#pragma unroll
        for (int rr = 0; rr < 16; ++rr) {
            int row = m0 + (wm << 5) + (rr & 3) + ((rr >> 2) << 3) + rb4;
            C[(size_t)row * 1536 + col] = ac[rr];
        }
    }
}

// ---------------- sLSTM activation (layer 2): + bias, h = sigm(o)*tanh(exp(i)*tanh(g)) ----------------
__global__ void k_slstm_act(const float* __restrict__ g, const float* __restrict__ bp,
                            unsigned short* __restrict__ hhi, unsigned short* __restrict__ hlo) {
    int idx = blockIdx.x * blockDim.x + threadIdx.x;
    int b = idx >> 7, j4 = (idx & 127) << 2;
    const float* r0 = g + (size_t)b * 1536 + j4;
    f32x4 gi = *(const f32x4*)r0 + *(const f32x4*)(bp + j4);
    f32x4 gg = *(const f32x4*)(r0 + 512) + *(const f32x4*)(bp + 1024 + j4);
    f32x4 go = *(const f32x4*)(r0 + 1024) + *(const f32x4*)(bp + 1536 + j4);
    ushort4 h, l;
    float x[4];
#pragma unroll
    for (int u = 0; u < 4; ++u)
        x[u] = tanhf(expf(gi[u]) * tanhf(gg[u])) / (1.f + expf(-go[u]));
    h.x = f2bf(x[0]); h.y = f2bf(x[1]); h.z = f2bf(x[2]); h.w = f2bf(x[3]);
    l.x = f2bf(x[0] - bf2f(h.x)); l.y = f2bf(x[1] - bf2f(h.y));
    l.z = f2bf(x[2] - bf2f(h.z)); l.w = f2bf(x[3] - bf2f(h.w));
    size_t o = (size_t)b * HID + j4;
    *(ushort4*)(hhi + o) = h;
    *(ushort4*)(hlo + o) = l;
}

// ---------------- mLSTM head math + layernorm (+optional fused final projection) ----------------
__global__ __launch_bounds__(512) void k_mlstm(
    const float* __restrict__ g0,
    const float* __restrict__ bq, const float* __restrict__ bk, const float* __restrict__ bv,
    const bf16* __restrict__ hinh, const bf16* __restrict__ hinl,
    const float* __restrict__ igw, const float* __restrict__ igb,
    const float* __restrict__ lng, const float* __restrict__ lnb,
    unsigned short* __restrict__ outh, unsigned short* __restrict__ outl,
    const float* __restrict__ opw, const float* __restrict__ opb, float* __restrict__ out)
{
    int b = blockIdx.x;
    int tid = threadIdx.x, head = tid >> 6, lane = tid & 63;

    const bf16*  hh = hinh + (size_t)b * HID;
    const bf16*  hl = hinl + (size_t)b * HID;
    const float* wrow = igw + head * HID;
    float s = 0.f;
#pragma unroll
    for (int k = 0; k < 8; ++k) {
        int p = lane + 64 * k;
        s += wrow[p] * (__bfloat162float(hh[p]) + __bfloat162float(hl[p]));
    }
#pragma unroll
    for (int off = 32; off; off >>= 1) s += __shfl_xor(s, off);
    float ig = expf(s + igb[head]);

    const float* r0 = g0 + (size_t)b * 1536;
    float q  = r0[tid] + bq[tid];
    float kk = r0[512 + tid] + bk[tid];
    float v  = r0[1024 + tid] + bv[tid];
    float kq = kk * q, vq = v * q;
#pragma unroll
    for (int off = 32; off; off >>= 1) { kq += __shfl_xor(kq, off); vq += __shfl_xor(vq, off); }
    float den = ig * (vq + 1.0f) + 1e-6f;
    float hv  = v * (ig * kq) / den;

    __shared__ float red[16];
    __shared__ float red2[8];
    float s1 = hv, s2 = hv * hv;
#pragma unroll
    for (int off = 32; off; off >>= 1) { s1 += __shfl_xor(s1, off); s2 += __shfl_xor(s2, off); }
    if (lane == 0) { red[head] = s1; red[8 + head] = s2; }
    __syncthreads();
    float t1 = 0.f, t2 = 0.f;
#pragma unroll
    for (int h2 = 0; h2 < 8; ++h2) { t1 += red[h2]; t2 += red[8 + h2]; }
    float mu  = t1 * (1.f / 512.f);
    float var = t2 * (1.f / 512.f) - mu * mu;
    float o = (hv - mu) * rsqrtf(var + 1e-5f) * lng[tid] + lnb[tid];

    if (out) {   // fused final projection (layer 3)
        float po = o * opw[tid];
#pragma unroll
        for (int off = 32; off; off >>= 1) po += __shfl_xor(po, off);
        if (lane == 0) red2[head] = po;
        __syncthreads();
        if (tid == 0) {
            float tt = 0.f;
#pragma unroll
            for (int h2 = 0; h2 < 8; ++h2) tt += red2[h2];
            out[b] = tt + opb[0];
        }
    } else {
        unsigned short oh = f2bf(o);
        size_t p = (size_t)b * HID + tid;
        outh[p] = oh;
        outl[p] = f2bf(o - bf2f(oh));
    }
}

extern "C" void kernel_launch(void* const* d_in, const int* in_sizes, int n_in,
                              void* d_out, int out_size, void* d_ws, size_t ws_size,
                              hipStream_t stream) {
    const float* V    = (const float*)d_in[0];
    const float* t    = (const float*)d_in[1];
    const float* ip_w = (const float*)d_in[2];
    const float* ip_b = (const float*)d_in[3];
    const float* op_w = (const float*)d_in[4];
    const float* op_b = (const float*)d_in[5];
    const float* s0_W = (const float*)d_in[6];
    const float* s0_b = (const float*)d_in[7];
    const float* s2_W = (const float*)d_in[9];
    const float* s2_b = (const float*)d_in[10];
    const float* m1_Wq = (const float*)d_in[12];
    const float* m1_Wk = (const float*)d_in[13];
    const float* m1_Wv = (const float*)d_in[14];
    const float* m1_bq = (const float*)d_in[15];
    const float* m1_bk = (const float*)d_in[16];
    const float* m1_bv = (const float*)d_in[17];
    const float* m1_igw = (const float*)d_in[18];
    const float* m1_igb = (const float*)d_in[19];
    const float* m1_lng = (const float*)d_in[22];
    const float* m1_lnb = (const float*)d_in[23];
    const float* m3_Wq = (const float*)d_in[24];
    const float* m3_Wk = (const float*)d_in[25];
    const float* m3_Wv = (const float*)d_in[26];
    const float* m3_bq = (const float*)d_in[27];
    const float* m3_bk = (const float*)d_in[28];
    const float* m3_bv = (const float*)d_in[29];
    const float* m3_igw = (const float*)d_in[30];
    const float* m3_igb = (const float*)d_in[31];
    const float* m3_lng = (const float*)d_in[34];
    const float* m3_lnb = (const float*)d_in[35];

    char* ws = (char*)d_ws;
    bf16* whi  = (bf16*)ws;                            // layout unchanged; s0 region unused
    bf16* wlo  = (bf16*)(ws + 7340032);
    bf16* hAhi = (bf16*)(ws + 14680064);
    bf16* hAlo = (bf16*)(ws + 16777216);
    bf16* hBhi = (bf16*)(ws + 18874368);
    bf16* hBlo = (bf16*)(ws + 20971520);
    float* gq  = (float*)(ws + 23068672);              // [B][1536] f32 gates/qkv
    float* uV  = (float*)(ws + 35651584);              // [1536] rank-2 GEMV results
    float* uT  = uV + 1536;
    float* uC  = uT + 1536;

    CvtArgs ca;
    ca.src[0] = s2_W;
    ca.src[1] = m1_Wq; ca.src[2] = m1_Wk; ca.src[3] = m1_Wv;
    ca.src[4] = m3_Wq; ca.src[5] = m3_Wk; ca.src[6] = m3_Wv;
    k_prep<<<2944, 256, 0, stream>>>(ca, (unsigned short*)whi, (unsigned short*)wlo,
                                     s0_W, s0_b, ip_w, ip_b, uV, uT, uC);

    // layer 0+1: fused (A generated in-kernel from rank-2 tables; hB side-written)
    k_gemm1<<<192, 512, 0, stream>>>(V, t, uV, uT, uC,
        whi + 2097152, whi + 2359296, whi + 2621440,
        wlo + 2097152, wlo + 2359296, wlo + 2621440,
        (unsigned short*)hBhi, (unsigned short*)hBlo, gq);
    k_mlstm<<<BATCH, 512, 0, stream>>>(gq, m1_bq, m1_bk, m1_bv, hBhi, hBlo,
                                       m1_igw, m1_igb, m1_lng, m1_lnb,
                                       (unsigned short*)hAhi, (unsigned short*)hAlo,
                                       nullptr, nullptr, nullptr);
    // layer 2: sLSTM
    k_gemm<<<192, 512, 0, stream>>>(hAhi, hAlo,
        whi + 1048576, whi + 1572864, whi + 1835008,
        wlo + 1048576, wlo + 1572864, wlo + 1835008, gq);
    k_slstm_act<<<1024, 256, 0, stream>>>(gq, s2_b, (unsigned short*)hBhi, (unsigned short*)hBlo);
    // layer 3: mLSTM + fused output projection
    k_gemm<<<192, 512, 0, stream>>>(hBhi, hBlo,
        whi + 2883584, whi + 3145728, whi + 3407872,
        wlo + 2883584, wlo + 3145728, wlo + 3407872, gq);
    k_mlstm<<<BATCH, 512, 0, stream>>>(gq, m3_bq, m3_bk, m3_bv, hBhi, hBlo,
                                       m3_igw, m3_igb, m3_lng, m3_lnb,
                                       nullptr, nullptr,
                                       op_w, op_b, (float*)d_out);
}

// Round 19
// 100.785 us; speedup vs baseline: 2.5404x; 2.5404x over previous
//
#include <hip/hip_runtime.h>
#include <hip/hip_bf16.h>

#define HID 512
#define BATCH 2048

typedef __bf16 bf16x8 __attribute__((ext_vector_type(8)));
typedef float f32x4 __attribute__((ext_vector_type(4)));
typedef float f32x16 __attribute__((ext_vector_type(16)));
typedef __hip_bfloat16 bf16;

__device__ inline unsigned short f2bf(float x) {
    bf16 h = __float2bfloat16(x);
    return __builtin_bit_cast(unsigned short, h);
}
__device__ inline float bf2f(unsigned short u) {
    return __bfloat162float(__builtin_bit_cast(bf16, u));
}

__device__ inline void gload16(const void* g, void* l) {
    __builtin_amdgcn_global_load_lds((const __attribute__((address_space(1))) void*)g,
                                     (__attribute__((address_space(3))) void*)l, 16, 0, 0);
}

// ---------------- prep: weight hi/lo split (s2, m1, m3) + layer-0 rank-2 GEMV ----------------
// Layer-0 trick: h0 = V*w0 + t*w1 + ipb exactly (rank 2), so
// gates0(row j) = V*(W.w0)[j] + t*(W.w1)[j] + (W.ipb + s0_b)[j]  -> 3 GEMVs over 1536 gate rows.
struct CvtArgs { const float* src[7]; };   // s2_W, m1 q/k/v, m3 q/k/v

__global__ void k_prep(CvtArgs a, unsigned short* __restrict__ hi, unsigned short* __restrict__ lo,
                       const float* __restrict__ s0W, const float* __restrict__ s0b,
                       const float* __restrict__ ipw, const float* __restrict__ ipb,
                       float* __restrict__ uV, float* __restrict__ uT, float* __restrict__ uC) {
    const int bid = blockIdx.x;
    if (bid < 2560) {   // cvt: 2,621,440 elems / 4 / 256
        int idx4 = (bid * 256 + threadIdx.x) << 2;
        int seg, off; size_t dst;
        if (idx4 < 1048576) { seg = 0; off = idx4; dst = 1048576 + idx4; }          // s2_W
        else { int r = idx4 - 1048576; seg = 1 + (r >> 18); off = r & 262143; dst = 2097152 + r; }
        f32x4 w = *(const f32x4*)(a.src[seg] + off);
        ushort4 h, l;
        h.x = f2bf(w[0]); h.y = f2bf(w[1]); h.z = f2bf(w[2]); h.w = f2bf(w[3]);
        l.x = f2bf(w[0] - bf2f(h.x)); l.y = f2bf(w[1] - bf2f(h.y));
        l.z = f2bf(w[2] - bf2f(h.z)); l.w = f2bf(w[3] - bf2f(h.w));
        *(ushort4*)(hi + dst) = h;
        *(ushort4*)(lo + dst) = l;
    } else {            // GEMV: 1536 gate rows (skip f-rows 512-1023), 4 waves/block
        const int w = threadIdx.x >> 6, lane = threadIdx.x & 63;
        const int r = (bid - 2560) * 4 + w;            // compact row 0..1535
        const int wr = r < 512 ? r : r + 512;          // W row (i / g / o segments)
        const float* Wp = s0W + (size_t)wr * HID + lane * 8;
        f32x4 wa = *(const f32x4*)Wp, wb = *(const f32x4*)(Wp + 4);
        const float* pw = ipw + lane * 16;             // [HID][2] interleaved
        f32x4 e0 = *(const f32x4*)pw,       e1 = *(const f32x4*)(pw + 4);
        f32x4 e2 = *(const f32x4*)(pw + 8), e3 = *(const f32x4*)(pw + 12);
        f32x4 ba = *(const f32x4*)(ipb + lane * 8), bb = *(const f32x4*)(ipb + lane * 8 + 4);
        float s0 = wa[0]*e0[0] + wa[1]*e0[2] + wa[2]*e1[0] + wa[3]*e1[2]
                 + wb[0]*e2[0] + wb[1]*e2[2] + wb[2]*e3[0] + wb[3]*e3[2];
        float s1 = wa[0]*e0[1] + wa[1]*e0[3] + wa[2]*e1[1] + wa[3]*e1[3]
                 + wb[0]*e2[1] + wb[1]*e2[3] + wb[2]*e3[1] + wb[3]*e3[3];
        float s2 = wa[0]*ba[0] + wa[1]*ba[1] + wa[2]*ba[2] + wa[3]*ba[3]
                 + wb[0]*bb[0] + wb[1]*bb[1] + wb[2]*bb[2] + wb[3]*bb[3];
#pragma unroll
        for (int off = 32; off; off >>= 1) {
            s0 += __shfl_xor(s0, off); s1 += __shfl_xor(s1, off); s2 += __shfl_xor(s2, off);
        }
        if (lane == 0) { uV[r] = s0; uT[r] = s1; uC[r] = s2 + s0b[wr]; }
    }
}

// ---------------- layer-0 sLSTM: gates from rank-2 GEMV result, fused activation ----------------
__global__ void k_slstm0(const float* __restrict__ V, const float* __restrict__ t,
                         const float* __restrict__ uV, const float* __restrict__ uT,
                         const float* __restrict__ uC,
                         unsigned short* __restrict__ hhi, unsigned short* __restrict__ hlo) {
    int idx = blockIdx.x * blockDim.x + threadIdx.x;   // B*HID/4
    int b = idx >> 7, j4 = (idx & 127) << 2;
    float vv = V[b], tt = t[b];
    f32x4 gi = vv * *(const f32x4*)(uV + j4)        + tt * *(const f32x4*)(uT + j4)        + *(const f32x4*)(uC + j4);
    f32x4 gg = vv * *(const f32x4*)(uV + 512 + j4)  + tt * *(const f32x4*)(uT + 512 + j4)  + *(const f32x4*)(uC + 512 + j4);
    f32x4 go = vv * *(const f32x4*)(uV + 1024 + j4) + tt * *(const f32x4*)(uT + 1024 + j4) + *(const f32x4*)(uC + 1024 + j4);
    ushort4 h, l;
    float x[4];
#pragma unroll
    for (int u = 0; u < 4; ++u)
        x[u] = tanhf(expf(gi[u]) * tanhf(gg[u])) / (1.f + expf(-go[u]));
    h.x = f2bf(x[0]); h.y = f2bf(x[1]); h.z = f2bf(x[2]); h.w = f2bf(x[3]);
    l.x = f2bf(x[0] - bf2f(h.x)); l.y = f2bf(x[1] - bf2f(h.y));
    l.z = f2bf(x[2] - bf2f(h.z)); l.w = f2bf(x[3] - bf2f(h.w));
    size_t o = (size_t)b * HID + j4;
    *(ushort4*)(hhi + o) = h;
    *(ushort4*)(hlo + o) = l;
}

// ---------------- native-K split-bf16 GEMM (deep 32-step K-loop, 3-buffer pipeline) ----------------
__global__ __launch_bounds__(256, 2) void k_gemm(
    const bf16* __restrict__ Ahi, const bf16* __restrict__ Alo,
    const bf16* __restrict__ Wh0, const bf16* __restrict__ Wh1, const bf16* __restrict__ Wh2,
    const bf16* __restrict__ Wl0, const bf16* __restrict__ Wl1, const bf16* __restrict__ Wl2,
    float* __restrict__ C)
{
    __shared__ __align__(16) bf16 lds[3][8192];   // 48 KB
    const int tid = threadIdx.x, w = tid >> 6, lane = tid & 63;

    const int bid = blockIdx.x;                   // 192 blocks: 8 XCD x 24 slots
    const int xcd = bid & 7, slot = bid >> 3;
    const int m0 = (xcd * 2 + slot / 12) * 128;
    const int n0 = (slot % 12) * 128;
    const int nseg = n0 >> 9, nloc = n0 & 511;
    const bf16* Wh = nseg == 0 ? Wh0 : (nseg == 1 ? Wh1 : Wh2);
    const bf16* Wl = nseg == 0 ? Wl0 : (nseg == 1 ? Wl1 : Wl2);

    const bf16* msrc = (w == 0) ? Ahi : (w == 1) ? Alo : (w == 2) ? Wh : Wl;
    const int rowbase = (w < 2) ? m0 : nloc;
    const size_t srow = (size_t)(rowbase + (lane & 31)) * HID + ((lane >> 5) << 3);

    auto STAGE = [&](int t) {
        bf16* db = &lds[t % 3][0] + (w << 11) + (lane << 3);
        const bf16* gp = msrc + srow + (t << 4);
#pragma unroll
        for (int p = 0; p < 4; ++p)
            gload16(gp + (size_t)(p << 5) * HID, db + (p << 9));
    };

    const int wm = w >> 1, wn = w & 1;
    const int la = lane << 3;
    f32x16 acc00 = {}, acc01 = {}, acc10 = {}, acc11 = {};

    STAGE(0);
    STAGE(1);
    for (int t = 0; t < 32; ++t) {
        if (t < 31)
            asm volatile("s_waitcnt vmcnt(4) lgkmcnt(0)\n\ts_barrier" ::: "memory");
        else
            asm volatile("s_waitcnt vmcnt(0) lgkmcnt(0)\n\ts_barrier" ::: "memory");
        if (t < 30) STAGE(t + 2);
        const bf16* lb = &lds[t % 3][0];
        bf16x8 ah0 = *(const bf16x8*)(lb + ((2 * wm    ) << 9) + la);
        bf16x8 ah1 = *(const bf16x8*)(lb + ((2 * wm + 1) << 9) + la);
        bf16x8 al0 = *(const bf16x8*)(lb + ((4 + 2 * wm    ) << 9) + la);
        bf16x8 al1 = *(const bf16x8*)(lb + ((4 + 2 * wm + 1) << 9) + la);
        bf16x8 wh0 = *(const bf16x8*)(lb + ((8 + 2 * wn    ) << 9) + la);
        bf16x8 wh1 = *(const bf16x8*)(lb + ((8 + 2 * wn + 1) << 9) + la);
        bf16x8 wl0 = *(const bf16x8*)(lb + ((12 + 2 * wn    ) << 9) + la);
        bf16x8 wl1 = *(const bf16x8*)(lb + ((12 + 2 * wn + 1) << 9) + la);
        __builtin_amdgcn_s_setprio(1);
        acc00 = __builtin_amdgcn_mfma_f32_32x32x16_bf16(ah0, wh0, acc00, 0, 0, 0);
        acc01 = __builtin_amdgcn_mfma_f32_32x32x16_bf16(ah0, wh1, acc01, 0, 0, 0);
        acc10 = __builtin_amdgcn_mfma_f32_32x32x16_bf16(ah1, wh0, acc10, 0, 0, 0);
        acc11 = __builtin_amdgcn_mfma_f32_32x32x16_bf16(ah1, wh1, acc11, 0, 0, 0);
        acc00 = __builtin_amdgcn_mfma_f32_32x32x16_bf16(al0, wh0, acc00, 0, 0, 0);
        acc01 = __builtin_amdgcn_mfma_f32_32x32x16_bf16(al0, wh1, acc01, 0, 0, 0);
        acc10 = __builtin_amdgcn_mfma_f32_32x32x16_bf16(al1, wh0, acc10, 0, 0, 0);
        acc11 = __builtin_amdgcn_mfma_f32_32x32x16_bf16(al1, wh1, acc11, 0, 0, 0);
        acc00 = __builtin_amdgcn_mfma_f32_32x32x16_bf16(ah0, wl0, acc00, 0, 0, 0);
        acc01 = __builtin_amdgcn_mfma_f32_32x32x16_bf16(ah0, wl1, acc01, 0, 0, 0);
        acc10 = __builtin_amdgcn_mfma_f32_32x32x16_bf16(ah1, wl0, acc10, 0, 0, 0);
        acc11 = __builtin_amdgcn_mfma_f32_32x32x16_bf16(ah1, wl1, acc11, 0, 0, 0);
        __builtin_amdgcn_s_setprio(0);
    }

    const f32x16* accs[2][2] = { { &acc00, &acc01 }, { &acc10, &acc11 } };
#pragma unroll
    for (int fi = 0; fi < 2; ++fi)
#pragma unroll
        for (int fj = 0; fj < 2; ++fj) {
            const f32x16& ac = *accs[fi][fj];
            const int col = n0 + ((2 * wn + fj) << 5) + (lane & 31);
            const int rbase = m0 + ((2 * wm + fi) << 5) + ((lane >> 5) << 2);
#pragma unroll
            for (int rr = 0; rr < 16; ++rr) {
                int row = rbase + (rr & 3) + ((rr >> 2) << 3);
                C[(size_t)row * 1536 + col] = ac[rr];
            }
        }
}

// ---------------- sLSTM activation (layer 2): + bias, h = sigm(o)*tanh(exp(i)*tanh(g)) ----------------
__global__ void k_slstm_act(const float* __restrict__ g, const float* __restrict__ bp,
                            unsigned short* __restrict__ hhi, unsigned short* __restrict__ hlo) {
    int idx = blockIdx.x * blockDim.x + threadIdx.x;
    int b = idx >> 7, j4 = (idx & 127) << 2;
    const float* r0 = g + (size_t)b * 1536 + j4;
    f32x4 gi = *(const f32x4*)r0 + *(const f32x4*)(bp + j4);
    f32x4 gg = *(const f32x4*)(r0 + 512) + *(const f32x4*)(bp + 1024 + j4);
    f32x4 go = *(const f32x4*)(r0 + 1024) + *(const f32x4*)(bp + 1536 + j4);
    ushort4 h, l;
    float x[4];
#pragma unroll
    for (int u = 0; u < 4; ++u)
        x[u] = tanhf(expf(gi[u]) * tanhf(gg[u])) / (1.f + expf(-go[u]));
    h.x = f2bf(x[0]); h.y = f2bf(x[1]); h.z = f2bf(x[2]); h.w = f2bf(x[3]);
    l.x = f2bf(x[0] - bf2f(h.x)); l.y = f2bf(x[1] - bf2f(h.y));
    l.z = f2bf(x[2] - bf2f(h.z)); l.w = f2bf(x[3] - bf2f(h.w));
    size_t o = (size_t)b * HID + j4;
    *(ushort4*)(hhi + o) = h;
    *(ushort4*)(hlo + o) = l;
}

// ---------------- mLSTM head math + layernorm (+optional fused final projection) ----------------
__global__ __launch_bounds__(512) void k_mlstm(
    const float* __restrict__ g0,
    const float* __restrict__ bq, const float* __restrict__ bk, const float* __restrict__ bv,
    const bf16* __restrict__ hinh, const bf16* __restrict__ hinl,
    const float* __restrict__ igw, const float* __restrict__ igb,
    const float* __restrict__ lng, const float* __restrict__ lnb,
    unsigned short* __restrict__ outh, unsigned short* __restrict__ outl,
    const float* __restrict__ opw, const float* __restrict__ opb, float* __restrict__ out)
{
    int b = blockIdx.x;
    int tid = threadIdx.x, head = tid >> 6, lane = tid & 63;

    // input gate on hi part only: ig differs by factor exp(w.hl) ~ 1+2^-17 — negligible
    const bf16*  hh = hinh + (size_t)b * HID;
    const float* wrow = igw + head * HID;
    float s = 0.f;
#pragma unroll
    for (int k = 0; k < 8; ++k) {
        int p = lane + 64 * k;
        s += wrow[p] * __bfloat162float(hh[p]);
    }
#pragma unroll
    for (int off = 32; off; off >>= 1) s += __shfl_xor(s, off);
    float ig = expf(s + igb[head]);

    const float* r0 = g0 + (size_t)b * 1536;
    float q  = r0[tid] + bq[tid];
    float kk = r0[512 + tid] + bk[tid];
    float v  = r0[1024 + tid] + bv[tid];
    float kq = kk * q, vq = v * q;
#pragma unroll
    for (int off = 32; off; off >>= 1) { kq += __shfl_xor(kq, off); vq += __shfl_xor(vq, off); }
    float den = ig * (vq + 1.0f) + 1e-6f;
    float hv  = v * (ig * kq) / den;

    __shared__ float red[16];
    __shared__ float red2[8];
    float s1 = hv, s2 = hv * hv;
#pragma unroll
    for (int off = 32; off; off >>= 1) { s1 += __shfl_xor(s1, off); s2 += __shfl_xor(s2, off); }
    if (lane == 0) { red[head] = s1; red[8 + head] = s2; }
    __syncthreads();
    float t1 = 0.f, t2 = 0.f;
#pragma unroll
    for (int h2 = 0; h2 < 8; ++h2) { t1 += red[h2]; t2 += red[8 + h2]; }
    float mu  = t1 * (1.f / 512.f);
    float var = t2 * (1.f / 512.f) - mu * mu;
    float o = (hv - mu) * rsqrtf(var + 1e-5f) * lng[tid] + lnb[tid];

    if (out) {   // fused final projection (layer 3)
        float po = o * opw[tid];
#pragma unroll
        for (int off = 32; off; off >>= 1) po += __shfl_xor(po, off);
        if (lane == 0) red2[head] = po;
        __syncthreads();
        if (tid == 0) {
            float tt = 0.f;
#pragma unroll
            for (int h2 = 0; h2 < 8; ++h2) tt += red2[h2];
            out[b] = tt + opb[0];
        }
    } else {
        unsigned short oh = f2bf(o);
        size_t p = (size_t)b * HID + tid;
        outh[p] = oh;
        outl[p] = f2bf(o - bf2f(oh));
    }
}

extern "C" void kernel_launch(void* const* d_in, const int* in_sizes, int n_in,
                              void* d_out, int out_size, void* d_ws, size_t ws_size,
                              hipStream_t stream) {
    const float* V    = (const float*)d_in[0];
    const float* t    = (const float*)d_in[1];
    const float* ip_w = (const float*)d_in[2];
    const float* ip_b = (const float*)d_in[3];
    const float* op_w = (const float*)d_in[4];
    const float* op_b = (const float*)d_in[5];
    const float* s0_W = (const float*)d_in[6];
    const float* s0_b = (const float*)d_in[7];
    const float* s2_W = (const float*)d_in[9];
    const float* s2_b = (const float*)d_in[10];
    const float* m1_Wq = (const float*)d_in[12];
    const float* m1_Wk = (const float*)d_in[13];
    const float* m1_Wv = (const float*)d_in[14];
    const float* m1_bq = (const float*)d_in[15];
    const float* m1_bk = (const float*)d_in[16];
    const float* m1_bv = (const float*)d_in[17];
    const float* m1_igw = (const float*)d_in[18];
    const float* m1_igb = (const float*)d_in[19];
    const float* m1_lng = (const float*)d_in[22];
    const float* m1_lnb = (const float*)d_in[23];
    const float* m3_Wq = (const float*)d_in[24];
    const float* m3_Wk = (const float*)d_in[25];
    const float* m3_Wv = (const float*)d_in[26];
    const float* m3_bq = (const float*)d_in[27];
    const float* m3_bk = (const float*)d_in[28];
    const float* m3_bv = (const float*)d_in[29];
    const float* m3_igw = (const float*)d_in[30];
    const float* m3_igb = (const float*)d_in[31];
    const float* m3_lng = (const float*)d_in[34];
    const float* m3_lnb = (const float*)d_in[35];

    char* ws = (char*)d_ws;
    bf16* whi  = (bf16*)ws;
    bf16* wlo  = (bf16*)(ws + 7340032);
    bf16* hAhi = (bf16*)(ws + 14680064);
    bf16* hAlo = (bf16*)(ws + 16777216);
    bf16* hBhi = (bf16*)(ws + 18874368);
    bf16* hBlo = (bf16*)(ws + 20971520);
    float* gq  = (float*)(ws + 23068672);
    float* uV  = (float*)(ws + 35651584);
    float* uT  = uV + 1536;
    float* uC  = uT + 1536;

    CvtArgs ca;
    ca.src[0] = s2_W;
    ca.src[1] = m1_Wq; ca.src[2] = m1_Wk; ca.src[3] = m1_Wv;
    ca.src[4] = m3_Wq; ca.src[5] = m3_Wk; ca.src[6] = m3_Wv;
    k_prep<<<2944, 256, 0, stream>>>(ca, (unsigned short*)whi, (unsigned short*)wlo,
                                     s0_W, s0_b, ip_w, ip_b, uV, uT, uC);

    // layer 0: sLSTM via rank-2 trick (no GEMM)
    k_slstm0<<<1024, 256, 0, stream>>>(V, t, uV, uT, uC,
                                       (unsigned short*)hBhi, (unsigned short*)hBlo);
    // layer 1: mLSTM (fused q|k|v)
    k_gemm<<<192, 256, 0, stream>>>(hBhi, hBlo,
        whi + 2097152, whi + 2359296, whi + 2621440,
        wlo + 2097152, wlo + 2359296, wlo + 2621440, gq);
    k_mlstm<<<BATCH, 512, 0, stream>>>(gq, m1_bq, m1_bk, m1_bv, hBhi, hBlo,
                                       m1_igw, m1_igb, m1_lng, m1_lnb,
                                       (unsigned short*)hAhi, (unsigned short*)hAlo,
                                       nullptr, nullptr, nullptr);
    // layer 2: sLSTM
    k_gemm<<<192, 256, 0, stream>>>(hAhi, hAlo,
        whi + 1048576, whi + 1572864, whi + 1835008,
        wlo + 1048576, wlo + 1572864, wlo + 1835008, gq);
    k_slstm_act<<<1024, 256, 0, stream>>>(gq, s2_b, (unsigned short*)hBhi, (unsigned short*)hBlo);
    // layer 3: mLSTM + fused output projection
    k_gemm<<<192, 256, 0, stream>>>(hBhi, hBlo,
        whi + 2883584, whi + 3145728, whi + 3407872,
        wlo + 2883584, wlo + 3145728, wlo + 3407872, gq);
    k_mlstm<<<BATCH, 512, 0, stream>>>(gq, m3_bq, m3_bk, m3_bv, hBhi, hBlo,
                                       m3_igw, m3_igb, m3_lng, m3_lnb,
                                       nullptr, nullptr,
                                       op_w, op_b, (float*)d_out);
}

// Round 20
// 99.718 us; speedup vs baseline: 2.5676x; 1.0107x over previous
//
#include <hip/hip_runtime.h>
#include <hip/hip_bf16.h>

#define HID 512
#define BATCH 2048

typedef __bf16 bf16x8 __attribute__((ext_vector_type(8)));
typedef float f32x4 __attribute__((ext_vector_type(4)));
typedef float f32x16 __attribute__((ext_vector_type(16)));
typedef __hip_bfloat16 bf16;

__device__ inline unsigned short f2bf(float x) {
    bf16 h = __float2bfloat16(x);
    return __builtin_bit_cast(unsigned short, h);
}
__device__ inline float bf2f(unsigned short u) {
    return __bfloat162float(__builtin_bit_cast(bf16, u));
}

__device__ inline void gload16(const void* g, void* l) {
    __builtin_amdgcn_global_load_lds((const __attribute__((address_space(1))) void*)g,
                                     (__attribute__((address_space(3))) void*)l, 16, 0, 0);
}

// ---------------- prep: weight hi/lo split (s2, m1, m3) + layer-0 rank-2 GEMV ----------------
struct CvtArgs { const float* src[7]; };   // s2_W, m1 q/k/v, m3 q/k/v

__global__ void k_prep(CvtArgs a, unsigned short* __restrict__ hi, unsigned short* __restrict__ lo,
                       const float* __restrict__ s0W, const float* __restrict__ s0b,
                       const float* __restrict__ ipw, const float* __restrict__ ipb,
                       float* __restrict__ uV, float* __restrict__ uT, float* __restrict__ uC) {
    const int bid = blockIdx.x;
    if (bid < 2560) {   // cvt: 2,621,440 elems / 4 / 256
        int idx4 = (bid * 256 + threadIdx.x) << 2;
        int seg, off; size_t dst;
        if (idx4 < 1048576) { seg = 0; off = idx4; dst = 1048576 + idx4; }          // s2_W
        else { int r = idx4 - 1048576; seg = 1 + (r >> 18); off = r & 262143; dst = 2097152 + r; }
        f32x4 w = *(const f32x4*)(a.src[seg] + off);
        ushort4 h, l;
        h.x = f2bf(w[0]); h.y = f2bf(w[1]); h.z = f2bf(w[2]); h.w = f2bf(w[3]);
        l.x = f2bf(w[0] - bf2f(h.x)); l.y = f2bf(w[1] - bf2f(h.y));
        l.z = f2bf(w[2] - bf2f(h.z)); l.w = f2bf(w[3] - bf2f(h.w));
        *(ushort4*)(hi + dst) = h;
        *(ushort4*)(lo + dst) = l;
    } else {            // GEMV: 1536 gate rows (skip f-rows 512-1023), 4 waves/block
        const int w = threadIdx.x >> 6, lane = threadIdx.x & 63;
        const int r = (bid - 2560) * 4 + w;            // compact row 0..1535
        const int wr = r < 512 ? r : r + 512;          // W row (i / g / o segments)
        const float* Wp = s0W + (size_t)wr * HID + lane * 8;
        f32x4 wa = *(const f32x4*)Wp, wb = *(const f32x4*)(Wp + 4);
        const float* pw = ipw + lane * 16;             // [HID][2] interleaved
        f32x4 e0 = *(const f32x4*)pw,       e1 = *(const f32x4*)(pw + 4);
        f32x4 e2 = *(const f32x4*)(pw + 8), e3 = *(const f32x4*)(pw + 12);
        f32x4 ba = *(const f32x4*)(ipb + lane * 8), bb = *(const f32x4*)(ipb + lane * 8 + 4);
        float s0 = wa[0]*e0[0] + wa[1]*e0[2] + wa[2]*e1[0] + wa[3]*e1[2]
                 + wb[0]*e2[0] + wb[1]*e2[2] + wb[2]*e3[0] + wb[3]*e3[2];
        float s1 = wa[0]*e0[1] + wa[1]*e0[3] + wa[2]*e1[1] + wa[3]*e1[3]
                 + wb[0]*e2[1] + wb[1]*e2[3] + wb[2]*e3[1] + wb[3]*e3[3];
        float s2 = wa[0]*ba[0] + wa[1]*ba[1] + wa[2]*ba[2] + wa[3]*ba[3]
                 + wb[0]*bb[0] + wb[1]*bb[1] + wb[2]*bb[2] + wb[3]*bb[3];
#pragma unroll
        for (int off = 32; off; off >>= 1) {
            s0 += __shfl_xor(s0, off); s1 += __shfl_xor(s1, off); s2 += __shfl_xor(s2, off);
        }
        if (lane == 0) { uV[r] = s0; uT[r] = s1; uC[r] = s2 + s0b[wr]; }
    }
}

// ---------------- layer-0 sLSTM: gates from rank-2 GEMV result, fused activation ----------------
__global__ void k_slstm0(const float* __restrict__ V, const float* __restrict__ t,
                         const float* __restrict__ uV, const float* __restrict__ uT,
                         const float* __restrict__ uC,
                         unsigned short* __restrict__ hhi, unsigned short* __restrict__ hlo) {
    int idx = blockIdx.x * blockDim.x + threadIdx.x;   // B*HID/4
    int b = idx >> 7, j4 = (idx & 127) << 2;
    float vv = V[b], tt = t[b];
    f32x4 gi = vv * *(const f32x4*)(uV + j4)        + tt * *(const f32x4*)(uT + j4)        + *(const f32x4*)(uC + j4);
    f32x4 gg = vv * *(const f32x4*)(uV + 512 + j4)  + tt * *(const f32x4*)(uT + 512 + j4)  + *(const f32x4*)(uC + 512 + j4);
    f32x4 go = vv * *(const f32x4*)(uV + 1024 + j4) + tt * *(const f32x4*)(uT + 1024 + j4) + *(const f32x4*)(uC + 1024 + j4);
    ushort4 h, l;
    float x[4];
#pragma unroll
    for (int u = 0; u < 4; ++u)
        x[u] = tanhf(expf(gi[u]) * tanhf(gg[u])) / (1.f + expf(-go[u]));
    h.x = f2bf(x[0]); h.y = f2bf(x[1]); h.z = f2bf(x[2]); h.w = f2bf(x[3]);
    l.x = f2bf(x[0] - bf2f(h.x)); l.y = f2bf(x[1] - bf2f(h.y));
    l.z = f2bf(x[2] - bf2f(h.z)); l.w = f2bf(x[3] - bf2f(h.w));
    size_t o = (size_t)b * HID + j4;
    *(ushort4*)(hhi + o) = h;
    *(ushort4*)(hlo + o) = l;
}

// ---------------- native-K split-bf16 GEMM: BK=32, 16 steps, 3-buffer pipeline ----------------
// C[2048][1536] = Ah*Wh + Al*Wh + Ah*Wl over K=512.  Block 128x128, 4 waves.
// LDS buffer (32KB) = 32 chunks of 1KB; chunk c = (m<<3)+(rb<<1)+ks, m: 0=Ah,1=Al,2=Wh,3=Wl,
// rb=rowblock 0..3, ks=k-subgroup 0..1.  Chunk: lane l <-> row (l&31), k = 16*ks + 8*(l>>5)..+8.
// Wave w stages matrix w (8 gload16/step).  24 MFMAs per barrier (2 ks x 12).
// vmcnt: steady retire stage(t) -> vmcnt(8); t=15 -> vmcnt(0).  STAGE stops at t=13.
__global__ __launch_bounds__(256) void k_gemm(
    const bf16* __restrict__ Ahi, const bf16* __restrict__ Alo,
    const bf16* __restrict__ Wh0, const bf16* __restrict__ Wh1, const bf16* __restrict__ Wh2,
    const bf16* __restrict__ Wl0, const bf16* __restrict__ Wl1, const bf16* __restrict__ Wl2,
    float* __restrict__ C)
{
    __shared__ __align__(16) bf16 lds[3][16384];   // 96 KB
    const int tid = threadIdx.x, w = tid >> 6, lane = tid & 63;

    const int bid = blockIdx.x;                   // 192 blocks: 8 XCD x 24 slots
    const int xcd = bid & 7, slot = bid >> 3;
    const int m0 = (xcd * 2 + slot / 12) * 128;
    const int n0 = (slot % 12) * 128;
    const int nseg = n0 >> 9, nloc = n0 & 511;
    const bf16* Wh = nseg == 0 ? Wh0 : (nseg == 1 ? Wh1 : Wh2);
    const bf16* Wl = nseg == 0 ? Wl0 : (nseg == 1 ? Wl1 : Wl2);

    const bf16* msrc = (w == 0) ? Ahi : (w == 1) ? Alo : (w == 2) ? Wh : Wl;
    const int rowbase = (w < 2) ? m0 : nloc;
    const size_t srow = (size_t)(rowbase + (lane & 31)) * HID + ((lane >> 5) << 3);

    auto STAGE = [&](int t) {
        bf16* db = &lds[t % 3][0] + (w << 12) + (lane << 3);   // chunk base (m=w, rb=0, ks=0)
        const bf16* gp = msrc + srow + (t << 5);
#pragma unroll
        for (int rb = 0; rb < 4; ++rb)
#pragma unroll
            for (int ks = 0; ks < 2; ++ks)
                gload16(gp + (size_t)(rb << 5) * HID + (ks << 4),
                        db + (((rb << 1) + ks) << 9));
    };

    const int wm = w >> 1, wn = w & 1;
    const int la = lane << 3;
    f32x16 acc00 = {}, acc01 = {}, acc10 = {}, acc11 = {};

    STAGE(0);
    STAGE(1);
    for (int t = 0; t < 16; ++t) {
        if (t < 15)
            asm volatile("s_waitcnt vmcnt(8) lgkmcnt(0)\n\ts_barrier" ::: "memory");
        else
            asm volatile("s_waitcnt vmcnt(0) lgkmcnt(0)\n\ts_barrier" ::: "memory");
        if (t < 14) STAGE(t + 2);   // writes buf (t+2)%3 = (t-1)%3: reads drained above
        const bf16* lb = &lds[t % 3][0];
#pragma unroll
        for (int ks = 0; ks < 2; ++ks) {
            bf16x8 ah0 = *(const bf16x8*)(lb + ((((2*wm    ) << 1) + ks) << 9) + la);
            bf16x8 ah1 = *(const bf16x8*)(lb + ((((2*wm + 1) << 1) + ks) << 9) + la);
            bf16x8 al0 = *(const bf16x8*)(lb + ((8 + ((2*wm    ) << 1) + ks) << 9) + la);
            bf16x8 al1 = *(const bf16x8*)(lb + ((8 + ((2*wm + 1) << 1) + ks) << 9) + la);
            bf16x8 wh0 = *(const bf16x8*)(lb + ((16 + ((2*wn    ) << 1) + ks) << 9) + la);
            bf16x8 wh1 = *(const bf16x8*)(lb + ((16 + ((2*wn + 1) << 1) + ks) << 9) + la);
            bf16x8 wl0 = *(const bf16x8*)(lb + ((24 + ((2*wn    ) << 1) + ks) << 9) + la);
            bf16x8 wl1 = *(const bf16x8*)(lb + ((24 + ((2*wn + 1) << 1) + ks) << 9) + la);
            __builtin_amdgcn_s_setprio(1);
            acc00 = __builtin_amdgcn_mfma_f32_32x32x16_bf16(ah0, wh0, acc00, 0, 0, 0);
            acc01 = __builtin_amdgcn_mfma_f32_32x32x16_bf16(ah0, wh1, acc01, 0, 0, 0);
            acc10 = __builtin_amdgcn_mfma_f32_32x32x16_bf16(ah1, wh0, acc10, 0, 0, 0);
            acc11 = __builtin_amdgcn_mfma_f32_32x32x16_bf16(ah1, wh1, acc11, 0, 0, 0);
            acc00 = __builtin_amdgcn_mfma_f32_32x32x16_bf16(al0, wh0, acc00, 0, 0, 0);
            acc01 = __builtin_amdgcn_mfma_f32_32x32x16_bf16(al0, wh1, acc01, 0, 0, 0);
            acc10 = __builtin_amdgcn_mfma_f32_32x32x16_bf16(al1, wh0, acc10, 0, 0, 0);
            acc11 = __builtin_amdgcn_mfma_f32_32x32x16_bf16(al1, wh1, acc11, 0, 0, 0);
            acc00 = __builtin_amdgcn_mfma_f32_32x32x16_bf16(ah0, wl0, acc00, 0, 0, 0);
            acc01 = __builtin_amdgcn_mfma_f32_32x32x16_bf16(ah0, wl1, acc01, 0, 0, 0);
            acc10 = __builtin_amdgcn_mfma_f32_32x32x16_bf16(ah1, wl0, acc10, 0, 0, 0);
            acc11 = __builtin_amdgcn_mfma_f32_32x32x16_bf16(ah1, wl1, acc11, 0, 0, 0);
            __builtin_amdgcn_s_setprio(0);
        }
    }

    // epilogue: D layout col = lane&31, row = (rr&3) + 8*(rr>>2) + 4*(lane>>5)
    const f32x16* accs[2][2] = { { &acc00, &acc01 }, { &acc10, &acc11 } };
#pragma unroll
    for (int fi = 0; fi < 2; ++fi)
#pragma unroll
        for (int fj = 0; fj < 2; ++fj) {
            const f32x16& ac = *accs[fi][fj];
            const int col = n0 + ((2 * wn + fj) << 5) + (lane & 31);
            const int rbase = m0 + ((2 * wm + fi) << 5) + ((lane >> 5) << 2);
#pragma unroll
            for (int rr = 0; rr < 16; ++rr) {
                int row = rbase + (rr & 3) + ((rr >> 2) << 3);
                C[(size_t)row * 1536 + col] = ac[rr];
            }
        }
}

// ---------------- sLSTM activation (layer 2): + bias, h = sigm(o)*tanh(exp(i)*tanh(g)) ----------------
__global__ void k_slstm_act(const float* __restrict__ g, const float* __restrict__ bp,
                            unsigned short* __restrict__ hhi, unsigned short* __restrict__ hlo) {
    int idx = blockIdx.x * blockDim.x + threadIdx.x;
    int b = idx >> 7, j4 = (idx & 127) << 2;
    const float* r0 = g + (size_t)b * 1536 + j4;
    f32x4 gi = *(const f32x4*)r0 + *(const f32x4*)(bp + j4);
    f32x4 gg = *(const f32x4*)(r0 + 512) + *(const f32x4*)(bp + 1024 + j4);
    f32x4 go = *(const f32x4*)(r0 + 1024) + *(const f32x4*)(bp + 1536 + j4);
    ushort4 h, l;
    float x[4];
#pragma unroll
    for (int u = 0; u < 4; ++u)
        x[u] = tanhf(expf(gi[u]) * tanhf(gg[u])) / (1.f + expf(-go[u]));
    h.x = f2bf(x[0]); h.y = f2bf(x[1]); h.z = f2bf(x[2]); h.w = f2bf(x[3]);
    l.x = f2bf(x[0] - bf2f(h.x)); l.y = f2bf(x[1] - bf2f(h.y));
    l.z = f2bf(x[2] - bf2f(h.z)); l.w = f2bf(x[3] - bf2f(h.w));
    size_t o = (size_t)b * HID + j4;
    *(ushort4*)(hhi + o) = h;
    *(ushort4*)(hlo + o) = l;
}

// ---------------- mLSTM head math + layernorm (+optional fused final projection) ----------------
__global__ __launch_bounds__(512) void k_mlstm(
    const float* __restrict__ g0,
    const float* __restrict__ bq, const float* __restrict__ bk, const float* __restrict__ bv,
    const bf16* __restrict__ hinh, const bf16* __restrict__ hinl,
    const float* __restrict__ igw, const float* __restrict__ igb,
    const float* __restrict__ lng, const float* __restrict__ lnb,
    unsigned short* __restrict__ outh, unsigned short* __restrict__ outl,
    const float* __restrict__ opw, const float* __restrict__ opb, float* __restrict__ out)
{
    int b = blockIdx.x;
    int tid = threadIdx.x, head = tid >> 6, lane = tid & 63;

    const bf16*  hh = hinh + (size_t)b * HID;
    const float* wrow = igw + head * HID;
    float s = 0.f;
#pragma unroll
    for (int k = 0; k < 8; ++k) {
        int p = lane + 64 * k;
        s += wrow[p] * __bfloat162float(hh[p]);
    }
#pragma unroll
    for (int off = 32; off; off >>= 1) s += __shfl_xor(s, off);
    float ig = expf(s + igb[head]);

    const float* r0 = g0 + (size_t)b * 1536;
    float q  = r0[tid] + bq[tid];
    float kk = r0[512 + tid] + bk[tid];
    float v  = r0[1024 + tid] + bv[tid];
    float kq = kk * q, vq = v * q;
#pragma unroll
    for (int off = 32; off; off >>= 1) { kq += __shfl_xor(kq, off); vq += __shfl_xor(vq, off); }
    float den = ig * (vq + 1.0f) + 1e-6f;
    float hv  = v * (ig * kq) / den;

    __shared__ float red[16];
    __shared__ float red2[8];
    float s1 = hv, s2 = hv * hv;
#pragma unroll
    for (int off = 32; off; off >>= 1) { s1 += __shfl_xor(s1, off); s2 += __shfl_xor(s2, off); }
    if (lane == 0) { red[head] = s1; red[8 + head] = s2; }
    __syncthreads();
    float t1 = 0.f, t2 = 0.f;
#pragma unroll
    for (int h2 = 0; h2 < 8; ++h2) { t1 += red[h2]; t2 += red[8 + h2]; }
    float mu  = t1 * (1.f / 512.f);
    float var = t2 * (1.f / 512.f) - mu * mu;
    float o = (hv - mu) * rsqrtf(var + 1e-5f) * lng[tid] + lnb[tid];

    if (out) {   // fused final projection (layer 3)
        float po = o * opw[tid];
#pragma unroll
        for (int off = 32; off; off >>= 1) po += __shfl_xor(po, off);
        if (lane == 0) red2[head] = po;
        __syncthreads();
        if (tid == 0) {
            float tt = 0.f;
#pragma unroll
            for (int h2 = 0; h2 < 8; ++h2) tt += red2[h2];
            out[b] = tt + opb[0];
        }
    } else {
        unsigned short oh = f2bf(o);
        size_t p = (size_t)b * HID + tid;
        outh[p] = oh;
        outl[p] = f2bf(o - bf2f(oh));
    }
}

extern "C" void kernel_launch(void* const* d_in, const int* in_sizes, int n_in,
                              void* d_out, int out_size, void* d_ws, size_t ws_size,
                              hipStream_t stream) {
    const float* V    = (const float*)d_in[0];
    const float* t    = (const float*)d_in[1];
    const float* ip_w = (const float*)d_in[2];
    const float* ip_b = (const float*)d_in[3];
    const float* op_w = (const float*)d_in[4];
    const float* op_b = (const float*)d_in[5];
    const float* s0_W = (const float*)d_in[6];
    const float* s0_b = (const float*)d_in[7];
    const float* s2_W = (const float*)d_in[9];
    const float* s2_b = (const float*)d_in[10];
    const float* m1_Wq = (const float*)d_in[12];
    const float* m1_Wk = (const float*)d_in[13];
    const float* m1_Wv = (const float*)d_in[14];
    const float* m1_bq = (const float*)d_in[15];
    const float* m1_bk = (const float*)d_in[16];
    const float* m1_bv = (const float*)d_in[17];
    const float* m1_igw = (const float*)d_in[18];
    const float* m1_igb = (const float*)d_in[19];
    const float* m1_lng = (const float*)d_in[22];
    const float* m1_lnb = (const float*)d_in[23];
    const float* m3_Wq = (const float*)d_in[24];
    const float* m3_Wk = (const float*)d_in[25];
    const float* m3_Wv = (const float*)d_in[26];
    const float* m3_bq = (const float*)d_in[27];
    const float* m3_bk = (const float*)d_in[28];
    const float* m3_bv = (const float*)d_in[29];
    const float* m3_igw = (const float*)d_in[30];
    const float* m3_igb = (const float*)d_in[31];
    const float* m3_lng = (const float*)d_in[34];
    const float* m3_lnb = (const float*)d_in[35];

    char* ws = (char*)d_ws;
    bf16* whi  = (bf16*)ws;
    bf16* wlo  = (bf16*)(ws + 7340032);
    bf16* hAhi = (bf16*)(ws + 14680064);
    bf16* hAlo = (bf16*)(ws + 16777216);
    bf16* hBhi = (bf16*)(ws + 18874368);
    bf16* hBlo = (bf16*)(ws + 20971520);
    float* gq  = (float*)(ws + 23068672);
    float* uV  = (float*)(ws + 35651584);
    float* uT  = uV + 1536;
    float* uC  = uT + 1536;

    CvtArgs ca;
    ca.src[0] = s2_W;
    ca.src[1] = m1_Wq; ca.src[2] = m1_Wk; ca.src[3] = m1_Wv;
    ca.src[4] = m3_Wq; ca.src[5] = m3_Wk; ca.src[6] = m3_Wv;
    k_prep<<<2944, 256, 0, stream>>>(ca, (unsigned short*)whi, (unsigned short*)wlo,
                                     s0_W, s0_b, ip_w, ip_b, uV, uT, uC);

    // layer 0: sLSTM via rank-2 trick (no GEMM)
    k_slstm0<<<1024, 256, 0, stream>>>(V, t, uV, uT, uC,
                                       (unsigned short*)hBhi, (unsigned short*)hBlo);
    // layer 1: mLSTM (fused q|k|v)
    k_gemm<<<192, 256, 0, stream>>>(hBhi, hBlo,
        whi + 2097152, whi + 2359296, whi + 2621440,
        wlo + 2097152, wlo + 2359296, wlo + 2621440, gq);
    k_mlstm<<<BATCH, 512, 0, stream>>>(gq, m1_bq, m1_bk, m1_bv, hBhi, hBlo,
                                       m1_igw, m1_igb, m1_lng, m1_lnb,
                                       (unsigned short*)hAhi, (unsigned short*)hAlo,
                                       nullptr, nullptr, nullptr);
    // layer 2: sLSTM
    k_gemm<<<192, 256, 0, stream>>>(hAhi, hAlo,
        whi + 1048576, whi + 1572864, whi + 1835008,
        wlo + 1048576, wlo + 1572864, wlo + 1835008, gq);
    k_slstm_act<<<1024, 256, 0, stream>>>(gq, s2_b, (unsigned short*)hBhi, (unsigned short*)hBlo);
    // layer 3: mLSTM + fused output projection
    k_gemm<<<192, 256, 0, stream>>>(hBhi, hBlo,
        whi + 2883584, whi + 3145728, whi + 3407872,
        wlo + 2883584, wlo + 3145728, wlo + 3407872, gq);
    k_mlstm<<<BATCH, 512, 0, stream>>>(gq, m3_bq, m3_bk, m3_bv, hBhi, hBlo,
                                       m3_igw, m3_igb, m3_lng, m3_lnb,
                                       nullptr, nullptr,
                                       op_w, op_b, (float*)d_out);
}